// Round 4
// baseline (61.245 us; speedup 1.0000x reference)
//
#include <hip/hip_runtime.h>

// x (16,16,64,64) f32, weight (16,64) f32, nodes (64,) f32 -> scalar f32.
constexpr int F_ = 16, N_ = 64;
constexpr int TOTAL = 16 * 16 * 64 * 64;         // 1,048,576 elements
constexpr int VEC = TOTAL / 4;                   // 262,144 float4
constexpr int THREADS = 256;
constexpr int BLOCKS = VEC / THREADS;            // 1024 blocks, 1 float4/thread
constexpr int NPART = BLOCKS * (THREADS / 64);   // 4096 wave partials

// Closed-form 5-point quartic B-spline window (validated: absmax 0.0 in R3).
// u = (x+3)*10.5 ; s = u - rint(u) in [-0.5,0.5]; nodes rint(u)-2 .. +2.
// w0=p^4, w1=1+4p+6p^2+4p^3-4p^4, w2=6s^4-15s^2+14.375, w3=w1(q), w4=q^4 (/24).
__global__ __launch_bounds__(THREADS) void spline_partial(
    const float* __restrict__ x,
    const float* __restrict__ weight,
    float* __restrict__ partials)
{
    const int tid  = threadIdx.x;
    const int lane = tid & 63;

    // f = (elem>>12)&15 ; elem = (blockIdx*256+tid)*4 -> f = (blockIdx>>2)&15.
    const int f = (blockIdx.x >> 2) & (F_ - 1);
    // One exp(weight) row held across the wave: lane l owns ew[f][l].
    const float roww = __expf(weight[f * N_ + lane]);

    const int idx4 = blockIdx.x * THREADS + tid;
    const float4 v = reinterpret_cast<const float4*>(x)[idx4];
    const float vals[4] = {v.x, v.y, v.z, v.w};

    float local = 0.0f;
    #pragma unroll
    for (int j = 0; j < 4; ++j) {
        const float u = fmaf(vals[j], 10.5f, 31.5f);
        const float r = rintf(u);
        const float s = u - r;                     // [-0.5, 0.5]
        const int n0 = (int)r - 2;

        const float p = 0.5f - s, q = 0.5f + s;
        const float p2 = p * p, q2 = q * q, s2 = s * s;
        float w[5];
        w[0] = p2 * p2;
        w[1] = 1.0f + p * (4.0f + p * (6.0f + p * (4.0f - 4.0f * p)));
        w[2] = fmaf(s2, fmaf(s2, 6.0f, -15.0f), 14.375f);
        w[3] = 1.0f + q * (4.0f + q * (6.0f + q * (4.0f - 4.0f * q)));
        w[4] = q2 * q2;

        float y = 0.0f;
        #pragma unroll
        for (int d = 0; d < 5; ++d) {
            const int n = n0 + d;
            // data-dependent shfl -> ds_bpermute (crossbar, conflict-free)
            const float ev = __shfl(roww, n & (N_ - 1), 64);
            const float wd = ((unsigned)n < (unsigned)N_) ? w[d] : 0.0f;
            y = fmaf(wd, ev, y);
        }
        local += __logf(fmaf(y, 1.0f / 24.0f, 1e-7f));
    }

    // wave-64 butterfly; one plain store per wave. No LDS, no barriers.
    #pragma unroll
    for (int off = 32; off > 0; off >>= 1)
        local += __shfl_down(local, off, 64);
    if (lane == 0)
        partials[(idx4 >> 6)] = local;   // 4096 wave partials
}

__global__ __launch_bounds__(1024) void reduce_partials(
    const float* __restrict__ partials, float* __restrict__ out)
{
    const int tid = threadIdx.x;
    const float4 v = reinterpret_cast<const float4*>(partials)[tid]; // 1024*4 = 4096
    float s = (v.x + v.y) + (v.z + v.w);
    #pragma unroll
    for (int off = 32; off > 0; off >>= 1)
        s += __shfl_down(s, off, 64);

    __shared__ float wpart[16];
    if ((tid & 63) == 0) wpart[tid >> 6] = s;
    __syncthreads();
    if (tid == 0) {
        float t = 0.0f;
        #pragma unroll
        for (int i = 0; i < 16; ++i) t += wpart[i];
        out[0] = t;
    }
}

extern "C" void kernel_launch(void* const* d_in, const int* in_sizes, int n_in,
                              void* d_out, int out_size, void* d_ws, size_t ws_size,
                              hipStream_t stream) {
    const float* x      = (const float*)d_in[0];
    const float* weight = (const float*)d_in[1];
    float* out      = (float*)d_out;
    float* partials = (float*)d_ws;   // 4096 floats of scratch

    spline_partial<<<BLOCKS, THREADS, 0, stream>>>(x, weight, partials);
    reduce_partials<<<1, 1024, 0, stream>>>(partials, out);
}